// Round 4
// baseline (52565.320 us; speedup 1.0000x reference)
//
#include <hip/hip_runtime.h>

// ReverseLSTMLayer: T=1024, B=32, I=1024, H=1024, fp32 in/out.
// d_out layout: outputs [T*B*H] | h_fin [B*H] | c_fin [B*H].
//
// Round 4: persistent kernel (256 blocks x 512 threads, 1 block/CU forced by
// 144KB LDS), W hi/lo fragment-major in LDS, c in registers, x reg-prefetch.
// NEW vs round 3: two-level tree grid barrier (16 same-XCD groups of 16,
// 256B-padded lines), relaxed RMW arrivals AND relaxed RMW polling (no
// per-poll cache invalidates), single acquire-side __threadfence per step.
// Split-bf16 3-pass MFMA numerics (proven absmax 0.0039).

constexpr int T_STEPS = 1024;
constexpr int BATCH   = 32;
constexpr int IN_DIM  = 1024;
constexpr int HID     = 1024;
constexpr int BH      = BATCH * HID;   // 32768
constexpr int NBLK    = 256;

typedef __attribute__((ext_vector_type(8))) short  short8;
typedef __attribute__((ext_vector_type(4))) float  f32x4;

__device__ __forceinline__ unsigned short f2bf(float f) {
    union { float f; unsigned u; } x; x.f = f;
    unsigned r = (x.u + 0x7fffu + ((x.u >> 16) & 1u)) >> 16;
    return (unsigned short)r;
}
__device__ __forceinline__ float bf2f(unsigned short h) {
    union { unsigned u; float f; } x; x.u = ((unsigned)h) << 16;
    return x.f;
}
__device__ __forceinline__ f32x4 mfma16(short8 a, short8 b, f32x4 c) {
    return __builtin_amdgcn_mfma_f32_16x16x32_bf16(a, b, c, 0, 0, 0);
}

__device__ __forceinline__ unsigned atomic_rmw_add(unsigned* p, unsigned v) {
    return __hip_atomic_fetch_add(p, v, __ATOMIC_RELAXED, __HIP_MEMORY_SCOPE_AGENT);
}

// ---------------- one-time converters ----------------

__global__ void convert_split(const float* __restrict__ src,
                              unsigned short* __restrict__ hi,
                              unsigned short* __restrict__ lo, int n4) {
    for (int i = blockIdx.x * blockDim.x + threadIdx.x; i < n4;
         i += gridDim.x * blockDim.x) {
        const float4 v = ((const float4*)src)[i];
        ushort4 h, l;
        float t;
        h.x = f2bf(v.x); t = v.x - bf2f(h.x); l.x = f2bf(t);
        h.y = f2bf(v.y); t = v.y - bf2f(h.y); l.y = f2bf(t);
        h.z = f2bf(v.z); t = v.z - bf2f(h.z); l.z = f2bf(t);
        h.w = f2bf(v.w); t = v.w - bf2f(h.w); l.w = f2bf(t);
        ((ushort4*)hi)[i] = h;
        ((ushort4*)lo)[i] = l;
    }
}

// Wpk[blk][half(hi=0,lo=1)][kstep 0..63][lane 0..63][8 elems].
// (blk, lane): m=lane&15, kg=(lane>>4)*8, row=(m>>2)*1024+blk*4+(m&3),
// k = kstep*32+kg; k<1024 -> W_ih, else W_hh.
__global__ void pack_W(const float* __restrict__ W_ih,
                       const float* __restrict__ W_hh,
                       unsigned short* __restrict__ Wpk) {
    const int i = blockIdx.x * blockDim.x + threadIdx.x;   // 0 .. 2,097,151
    const int lane = i & 63;
    const int s    = (i >> 6) & 63;
    const int half = (i >> 12) & 1;
    const int blk  = i >> 13;
    if (blk >= NBLK) return;
    const int m   = lane & 15;
    const int kg  = (lane >> 4) << 3;
    const int row = ((m >> 2) << 10) + (blk << 2) + (m & 3);
    const int k   = (s << 5) + kg;
    const float* src = (k < IN_DIM) ? (W_ih + (size_t)row * IN_DIM + k)
                                    : (W_hh + (size_t)row * HID + (k - IN_DIM));
    unsigned short v[8];
    #pragma unroll
    for (int e = 0; e < 8; ++e) {
        const float f = src[e];
        const unsigned short h = f2bf(f);
        v[e] = half ? f2bf(f - bf2f(h)) : h;
    }
    ushort4* dst = (ushort4*)(Wpk + (size_t)i * 8);
    dst[0] = make_ushort4(v[0], v[1], v[2], v[3]);
    dst[1] = make_ushort4(v[4], v[5], v[6], v[7]);
}

// h0 split, bias combine, barrier region reset (4096 uints).
__global__ void prep_state(const float* __restrict__ h0,
                           const float* __restrict__ b_ih,
                           const float* __restrict__ b_hh,
                           unsigned short* __restrict__ h_hi,
                           unsigned short* __restrict__ h_lo,
                           float* __restrict__ bias,
                           unsigned* __restrict__ bar) {
    const int i = blockIdx.x * blockDim.x + threadIdx.x;
    if (i < BH) {
        const float v = h0[i];
        const unsigned short hh = f2bf(v);
        h_hi[i] = hh;
        h_lo[i] = f2bf(v - bf2f(hh));
    }
    if (i < 4 * HID) bias[i] = b_ih[i] + b_hh[i];
    if (i < 4096) bar[i] = 0u;
}

// ---------------- persistent LSTM scan ----------------
// Dynamic LDS: [0,128KiB) W fragments [2][64][64][8] bf16; [128KiB,144KiB)
// reduce buffer float[16][256].
// Barrier layout in bar[] (unsigned, 64-uint = 256B padding):
//   grp_cnt[g]   = bar[g*64]          g = blk & 15 (same-XCD groups of 16)
//   grp_phase[g] = bar[1024 + g*64]
//   root_cnt     = bar[2048]
//   root_phase   = bar[2112]
__global__ __launch_bounds__(512, 2) void lstm_persistent(
    const unsigned short* __restrict__ x_hi,   // [T][32][1024]
    const unsigned short* __restrict__ x_lo,
    const unsigned short* __restrict__ Wpk,    // [256][2][64][64][8]
    unsigned short* __restrict__ hA_hi, unsigned short* __restrict__ hA_lo,
    unsigned short* __restrict__ hB_hi, unsigned short* __restrict__ hB_lo,
    const float* __restrict__ bias,            // [4096]
    const float* __restrict__ c0,              // [32][1024]
    float* __restrict__ out,
    unsigned* __restrict__ bar)
{
    extern __shared__ unsigned char smem[];
    float* red = (float*)(smem + 131072);

    const int tid  = threadIdx.x;
    const int wave = tid >> 6;
    const int lane = tid & 63;
    const int blk  = blockIdx.x;

    // One-time: copy this block's 128 KiB W slice into LDS (coalesced).
    {
        const uint4* src = (const uint4*)Wpk + (size_t)blk * 8192;
        uint4* dst = (uint4*)smem;
        #pragma unroll
        for (int r = 0; r < 16; ++r) dst[r * 512 + tid] = src[r * 512 + tid];
    }

    const int m16    = lane & 15;
    const int kg     = (lane >> 4) << 3;
    const int off_b0 = m16 * HID + (wave << 7) + kg;   // batches 0-15 frag base
    const int off_b1 = off_b0 + 16 * HID;              // batches 16-31
    const int wbyte  = lane << 4;

    // Per-thread persistent epilogue state (tid < 128): c + bias.
    float c_reg = 0.f;
    float bias_reg[4] = {0.f, 0.f, 0.f, 0.f};
    const int b_own   = tid >> 2;
    const int jj      = tid & 3;
    const int col_own = (blk << 2) + jj;
    const int idx_own = b_own * HID + col_own;
    if (tid < 128) {
        #pragma unroll
        for (int g = 0; g < 4; ++g) bias_reg[g] = bias[g * HID + col_own];
        c_reg = c0[idx_own];
    }

    // Barrier pointers (per-block constants).
    unsigned* const gcnt = bar + ((blk & 15) * 64);
    unsigned* const gph  = bar + 1024 + ((blk & 15) * 64);
    unsigned* const rcnt = bar + 2048;
    unsigned* const rph  = bar + 2112;

    __syncthreads();

    unsigned short* hin_hi  = hA_hi;
    unsigned short* hin_lo  = hA_lo;
    unsigned short* hout_hi = hB_hi;
    unsigned short* hout_lo = hB_lo;

    // Prefetch x fragments for the first step (t = T-1).
    short8 pxh0[4], pxh1[4], pxl0[4], pxl1[4];
    {
        const unsigned short* xh = x_hi + (size_t)(T_STEPS - 1) * BH;
        const unsigned short* xl = x_lo + (size_t)(T_STEPS - 1) * BH;
        #pragma unroll
        for (int sq = 0; sq < 4; ++sq) {
            pxh0[sq] = *(const short8*)(xh + off_b0 + (sq << 5));
            pxh1[sq] = *(const short8*)(xh + off_b1 + (sq << 5));
            pxl0[sq] = *(const short8*)(xl + off_b0 + (sq << 5));
            pxl1[sq] = *(const short8*)(xl + off_b1 + (sq << 5));
        }
    }

    unsigned phase = 0;

    for (int i = 0; i < T_STEPS; ++i) {
        const int t = T_STEPS - 1 - i;

        // Issue h loads first (longest latency).
        short8 hh0[4], hh1[4], hl0[4], hl1[4];
        #pragma unroll
        for (int sq = 0; sq < 4; ++sq) {
            hh0[sq] = *(const short8*)(hin_hi + off_b0 + (sq << 5));
            hh1[sq] = *(const short8*)(hin_hi + off_b1 + (sq << 5));
            hl0[sq] = *(const short8*)(hin_lo + off_b0 + (sq << 5));
            hl1[sq] = *(const short8*)(hin_lo + off_b1 + (sq << 5));
        }

        f32x4 acc0 = {0.f, 0.f, 0.f, 0.f};
        f32x4 acc1 = {0.f, 0.f, 0.f, 0.f};

        // x-part MFMAs with prefetched fragments (hide h-load latency).
        #pragma unroll
        for (int sq = 0; sq < 4; ++sq) {
            const int s = (wave << 2) + sq;
            const short8 whi = *(const short8*)(smem + (size_t)s * 1024 + wbyte);
            const short8 wlo = *(const short8*)(smem + (size_t)(64 + s) * 1024 + wbyte);
            acc0 = mfma16(whi, pxh0[sq], acc0);
            acc0 = mfma16(whi, pxl0[sq], acc0);
            acc0 = mfma16(wlo, pxh0[sq], acc0);
            acc1 = mfma16(whi, pxh1[sq], acc1);
            acc1 = mfma16(whi, pxl1[sq], acc1);
            acc1 = mfma16(wlo, pxh1[sq], acc1);
        }

        // Prefetch next step's x fragments.
        if (i + 1 < T_STEPS) {
            const unsigned short* xh = x_hi + (size_t)(t - 1) * BH;
            const unsigned short* xl = x_lo + (size_t)(t - 1) * BH;
            #pragma unroll
            for (int sq = 0; sq < 4; ++sq) {
                pxh0[sq] = *(const short8*)(xh + off_b0 + (sq << 5));
                pxh1[sq] = *(const short8*)(xh + off_b1 + (sq << 5));
                pxl0[sq] = *(const short8*)(xl + off_b0 + (sq << 5));
                pxl1[sq] = *(const short8*)(xl + off_b1 + (sq << 5));
            }
        }

        // h-part MFMAs.
        #pragma unroll
        for (int sq = 0; sq < 4; ++sq) {
            const int s = 32 + (wave << 2) + sq;
            const short8 whi = *(const short8*)(smem + (size_t)s * 1024 + wbyte);
            const short8 wlo = *(const short8*)(smem + (size_t)(64 + s) * 1024 + wbyte);
            acc0 = mfma16(whi, hh0[sq], acc0);
            acc0 = mfma16(whi, hl0[sq], acc0);
            acc0 = mfma16(wlo, hh0[sq], acc0);
            acc1 = mfma16(whi, hh1[sq], acc1);
            acc1 = mfma16(whi, hl1[sq], acc1);
            acc1 = mfma16(wlo, hh1[sq], acc1);
        }

        // Cross-wave reduce. C/D layout (m89): col=lane&15, row=4*(lane>>4)+r.
        {
            const int arow = (lane >> 4) << 2;
            const int acol = lane & 15;
            #pragma unroll
            for (int r = 0; r < 4; ++r) {
                red[((wave << 1) + 0) * 256 + (arow + r) * 16 + acol] = acc0[r];
                red[((wave << 1) + 1) * 256 + (arow + r) * 16 + acol] = acc1[r];
            }
        }
        __syncthreads();

        if (tid < 128) {
            const int mt  = b_own >> 4;
            const int c16 = b_own & 15;
            float val[4];
            #pragma unroll
            for (int g = 0; g < 4; ++g) {
                const int rr = ((g << 2) + jj) * 16 + c16;
                float sacc = 0.f;
                #pragma unroll
                for (int w = 0; w < 8; ++w) sacc += red[((w << 1) + mt) * 256 + rr];
                val[g] = sacc + bias_reg[g];
            }
            const float ig = 1.f / (1.f + __expf(-val[0]));
            const float fg = 1.f / (1.f + __expf(-val[1]));
            const float gg = tanhf(val[2]);
            const float og = 1.f / (1.f + __expf(-val[3]));
            c_reg = fg * c_reg + ig * gg;
            const float h_new = og * tanhf(c_reg);
            out[(size_t)t * BH + idx_own] = h_new;
            const unsigned short hh = f2bf(h_new);
            hout_hi[idx_own] = hh;
            hout_lo[idx_own] = f2bf(h_new - bf2f(hh));
            if (t == 0) out[(size_t)T_STEPS * BH + idx_own] = h_new;  // h_fin
            __threadfence();   // release: drain + write-back before arrival
        }

        // ---- two-level tree grid barrier (relaxed RMWs only) ----
        __syncthreads();
        if (tid == 0) {
            const unsigned target = phase + 1;
            const unsigned arrived = atomic_rmw_add(gcnt, 1u);
            if (arrived == 15u) {                 // group leader (last of 16)
                const unsigned r = atomic_rmw_add(rcnt, 1u);
                if (r == 15u) {                   // global last
                    atomic_rmw_add(rcnt, (unsigned)-16);   // reset via RMW
                    atomic_rmw_add(rph, 1u);
                } else {
                    while (atomic_rmw_add(rph, 0u) != target)
                        __builtin_amdgcn_s_sleep(2);
                }
                atomic_rmw_add(gcnt, (unsigned)-16);       // reset via RMW
                atomic_rmw_add(gph, 1u);
            } else {
                while (atomic_rmw_add(gph, 0u) != target)
                    __builtin_amdgcn_s_sleep(8);
            }
        }
        __syncthreads();
        __threadfence();   // acquire: invalidate stale h lines (once per step)
        phase += 1;

        // Swap h ping-pong.
        unsigned short* th = hin_hi; hin_hi = hout_hi; hout_hi = th;
        unsigned short* tl = hin_lo; hin_lo = hout_lo; hout_lo = tl;
    }

    if (tid < 128)
        out[(size_t)T_STEPS * BH + BH + idx_own] = c_reg;   // c_fin
}

// ---------------- fallback (round-1, known-good, slow) ----------------
__global__ __launch_bounds__(256) void lstm_step_fused(
    const float* __restrict__ x_t, const float* __restrict__ h_prev,
    const float* __restrict__ c_prev, float* __restrict__ c_out,
    float* __restrict__ h_out, const float* __restrict__ W_ih,
    const float* __restrict__ W_hh, const float* __restrict__ b_ih,
    const float* __restrict__ b_hh) {
    __shared__ float xs[IN_DIM];
    __shared__ float hs[HID];
    const int tid = threadIdx.x;
    const int b   = blockIdx.x >> 2;
    const int j   = ((blockIdx.x & 3) << 8) | tid;
    ((float4*)xs)[tid] = ((const float4*)(x_t    + (size_t)b * IN_DIM))[tid];
    ((float4*)hs)[tid] = ((const float4*)(h_prev + (size_t)b * HID))[tid];
    __syncthreads();
    float a0 = b_ih[j] + b_hh[j];
    float a1 = b_ih[HID + j] + b_hh[HID + j];
    float a2 = b_ih[2*HID + j] + b_hh[2*HID + j];
    float a3 = b_ih[3*HID + j] + b_hh[3*HID + j];
    {
        const float4* wi0 = (const float4*)(W_ih + (size_t)(0*HID + j) * IN_DIM);
        const float4* wi1 = (const float4*)(W_ih + (size_t)(1*HID + j) * IN_DIM);
        const float4* wi2 = (const float4*)(W_ih + (size_t)(2*HID + j) * IN_DIM);
        const float4* wi3 = (const float4*)(W_ih + (size_t)(3*HID + j) * IN_DIM);
        const float4* xs4 = (const float4*)xs;
        #pragma unroll 4
        for (int k = 0; k < IN_DIM / 4; ++k) {
            const float4 xv = xs4[k]; float4 w;
            w = wi0[k]; a0 += xv.x*w.x + xv.y*w.y + xv.z*w.z + xv.w*w.w;
            w = wi1[k]; a1 += xv.x*w.x + xv.y*w.y + xv.z*w.z + xv.w*w.w;
            w = wi2[k]; a2 += xv.x*w.x + xv.y*w.y + xv.z*w.z + xv.w*w.w;
            w = wi3[k]; a3 += xv.x*w.x + xv.y*w.y + xv.z*w.z + xv.w*w.w;
        }
    }
    {
        const float4* wh0 = (const float4*)(W_hh + (size_t)(0*HID + j) * HID);
        const float4* wh1 = (const float4*)(W_hh + (size_t)(1*HID + j) * HID);
        const float4* wh2 = (const float4*)(W_hh + (size_t)(2*HID + j) * HID);
        const float4* wh3 = (const float4*)(W_hh + (size_t)(3*HID + j) * HID);
        const float4* hs4 = (const float4*)hs;
        #pragma unroll 4
        for (int k = 0; k < HID / 4; ++k) {
            const float4 hv = hs4[k]; float4 w;
            w = wh0[k]; a0 += hv.x*w.x + hv.y*w.y + hv.z*w.z + hv.w*w.w;
            w = wh1[k]; a1 += hv.x*w.x + hv.y*w.y + hv.z*w.z + hv.w*w.w;
            w = wh2[k]; a2 += hv.x*w.x + hv.y*w.y + hv.z*w.z + hv.w*w.w;
            w = wh3[k]; a3 += hv.x*w.x + hv.y*w.y + hv.z*w.z + hv.w*w.w;
        }
    }
    const float ig = 1.0f / (1.0f + __expf(-a0));
    const float fg = 1.0f / (1.0f + __expf(-a1));
    const float gg = tanhf(a2);
    const float og = 1.0f / (1.0f + __expf(-a3));
    const size_t idx = (size_t)b * HID + j;
    const float c_new = fg * c_prev[idx] + ig * gg;
    c_out[idx] = c_new;
    h_out[idx] = og * tanhf(c_new);
}

__global__ void lstm_finalize(const float* __restrict__ h_fin_src,
                              const float* __restrict__ c_fin_src,
                              float* __restrict__ dst_h,
                              float* __restrict__ dst_c) {
    const int i = blockIdx.x * blockDim.x + threadIdx.x;
    if (i < BH) { dst_h[i] = h_fin_src[i]; dst_c[i] = c_fin_src[i]; }
}

// ---------------- host ----------------

extern "C" void kernel_launch(void* const* d_in, const int* in_sizes, int n_in,
                              void* d_out, int out_size, void* d_ws, size_t ws_size,
                              hipStream_t stream) {
    const float* input = (const float*)d_in[0];
    const float* h0    = (const float*)d_in[1];
    const float* c0    = (const float*)d_in[2];
    const float* W_ih  = (const float*)d_in[3];
    const float* W_hh  = (const float*)d_in[4];
    const float* b_ih  = (const float*)d_in[5];
    const float* b_hh  = (const float*)d_in[6];
    float* out = (float*)d_out;

    // ws carve-up (bytes)
    const size_t OFF_XHI   = 0;                         // 64 MiB
    const size_t OFF_XLO   = OFF_XHI + 67108864ULL;     // 64 MiB
    const size_t OFF_WPK   = OFF_XLO + 67108864ULL;     // 32 MiB
    const size_t OFF_BIAS  = OFF_WPK + 33554432ULL;     // 16 KiB
    const size_t OFF_HA_HI = OFF_BIAS + 16384ULL;       // 64 KiB each
    const size_t OFF_HA_LO = OFF_HA_HI + 65536ULL;
    const size_t OFF_HB_HI = OFF_HA_LO + 65536ULL;
    const size_t OFF_HB_LO = OFF_HB_HI + 65536ULL;
    const size_t OFF_BAR   = OFF_HB_LO + 65536ULL;      // 16 KiB barrier region
    const size_t NEED      = OFF_BAR + 16384ULL;

    if (ws_size >= NEED) {
        unsigned char* w = (unsigned char*)d_ws;
        unsigned short* x_hi  = (unsigned short*)(w + OFF_XHI);
        unsigned short* x_lo  = (unsigned short*)(w + OFF_XLO);
        unsigned short* Wpk   = (unsigned short*)(w + OFF_WPK);
        float*          bias  = (float*)(w + OFF_BIAS);
        unsigned short* hA_hi = (unsigned short*)(w + OFF_HA_HI);
        unsigned short* hA_lo = (unsigned short*)(w + OFF_HA_LO);
        unsigned short* hB_hi = (unsigned short*)(w + OFF_HB_HI);
        unsigned short* hB_lo = (unsigned short*)(w + OFF_HB_LO);
        unsigned*       bar   = (unsigned*)(w + OFF_BAR);

        hipLaunchKernelGGL(convert_split, dim3(4096), dim3(256), 0, stream,
                           input, x_hi, x_lo, T_STEPS * BH / 4);
        hipLaunchKernelGGL(pack_W, dim3(8192), dim3(256), 0, stream,
                           W_ih, W_hh, Wpk);
        hipLaunchKernelGGL(prep_state, dim3(128), dim3(256), 0, stream,
                           h0, b_ih, b_hh, hA_hi, hA_lo, bias, bar);

        hipFuncSetAttribute(reinterpret_cast<const void*>(lstm_persistent),
                            hipFuncAttributeMaxDynamicSharedMemorySize, 147456);
        hipLaunchKernelGGL(lstm_persistent, dim3(NBLK), dim3(512), 147456, stream,
                           x_hi, x_lo, Wpk, hA_hi, hA_lo, hB_hi, hB_lo,
                           bias, c0, out, bar);
    } else {
        // fallback: round-1 path (c scratch only)
        float* c_ws = (float*)d_ws;
        for (int t = T_STEPS - 1; t >= 0; --t) {
            const float* x_t = input + (size_t)t * BATCH * IN_DIM;
            const float* hp  = (t == T_STEPS - 1) ? h0 : out + (size_t)(t + 1) * BH;
            const float* cp  = (t == T_STEPS - 1) ? c0 : c_ws;
            hipLaunchKernelGGL(lstm_step_fused, dim3(128), dim3(256), 0, stream,
                               x_t, hp, cp, c_ws, out + (size_t)t * BH,
                               W_ih, W_hh, b_ih, b_hh);
        }
        hipLaunchKernelGGL(lstm_finalize, dim3(128), dim3(256), 0, stream,
                           out, c_ws,
                           out + (size_t)T_STEPS * BH,
                           out + (size_t)T_STEPS * BH + BH);
    }
}

// Round 6
// 14079.369 us; speedup vs baseline: 3.7335x; 3.7335x over previous
//
#include <hip/hip_runtime.h>

// ReverseLSTMLayer: T=1024, B=32, I=1024, H=1024, fp32 in/out.
// d_out layout: outputs [T*B*H] | h_fin [B*H] | c_fin [B*H].
//
// Round 6 (= round 5 + compile fix): persistent kernel (256 blocks x 512
// threads, 1 block/CU via 144KB LDS). W hi/lo fragment-major LDS-resident;
// c in registers; x reg-prefetch (plain cached loads). Fence-free cross-XCD
// handoff: h packed as uint(bf16hi<<16|bf16lo), exchanged via agent-scope
// RELAXED atomic stores/loads (coherence-point, no L2 invalidates anywhere);
// tree barrier with relaxed-RMW arrivals, RELEASE-RMW releases, relaxed-LOAD
// polling (+ bounded-spin RMW fallback against hangs). No __threadfence in
// the loop. Split-bf16 3-pass MFMA numerics (proven absmax 0.0039).

constexpr int T_STEPS = 1024;
constexpr int BATCH   = 32;
constexpr int IN_DIM  = 1024;
constexpr int HID     = 1024;
constexpr int BH      = BATCH * HID;   // 32768
constexpr int NBLK    = 256;

typedef __attribute__((ext_vector_type(8))) short  short8;
typedef __attribute__((ext_vector_type(4))) float  f32x4;

__device__ __forceinline__ unsigned short f2bf(float f) {
    union { float f; unsigned u; } x; x.f = f;
    unsigned r = (x.u + 0x7fffu + ((x.u >> 16) & 1u)) >> 16;
    return (unsigned short)r;
}
__device__ __forceinline__ float bf2f(unsigned short h) {
    union { unsigned u; float f; } x; x.u = ((unsigned)h) << 16;
    return x.f;
}
__device__ __forceinline__ f32x4 mfma16(short8 a, short8 b, f32x4 c) {
    return __builtin_amdgcn_mfma_f32_16x16x32_bf16(a, b, c, 0, 0, 0);
}

__device__ __forceinline__ unsigned rmw_add(unsigned* p, unsigned v, int order) {
    return __hip_atomic_fetch_add(p, v, order, __HIP_MEMORY_SCOPE_AGENT);
}
__device__ __forceinline__ unsigned flag_ld(const unsigned* p) {
    return __hip_atomic_load(p, __ATOMIC_RELAXED, __HIP_MEMORY_SCOPE_AGENT);
}
// Poll until *p >= target. Cheap relaxed loads; bounded-spin RMW fallback
// (RMW executes at the coherence point -> guaranteed fresh -> no hang).
template <int SLP>
__device__ __forceinline__ void poll_ge(unsigned* p, unsigned target) {
    int spins = 0;
    while (flag_ld(p) < target) {
        __builtin_amdgcn_s_sleep(SLP);
        if (++spins > 16384) {
            if (rmw_add(p, 0u, __ATOMIC_RELAXED) >= target) break;
            spins = 8192;
        }
    }
}

// Load 8 packed-h uints (as 4 ulongs, agent-scope) and unpack into
// bf16-hi / bf16-lo fragments.
__device__ __forceinline__ void unpack8(const unsigned long long* p,
                                        short8& hi, short8& lo) {
    const unsigned long long u0 = __hip_atomic_load(p + 0, __ATOMIC_RELAXED, __HIP_MEMORY_SCOPE_AGENT);
    const unsigned long long u1 = __hip_atomic_load(p + 1, __ATOMIC_RELAXED, __HIP_MEMORY_SCOPE_AGENT);
    const unsigned long long u2 = __hip_atomic_load(p + 2, __ATOMIC_RELAXED, __HIP_MEMORY_SCOPE_AGENT);
    const unsigned long long u3 = __hip_atomic_load(p + 3, __ATOMIC_RELAXED, __HIP_MEMORY_SCOPE_AGENT);
    unsigned a;
    a = (unsigned)u0;         hi[0] = (short)(a >> 16); lo[0] = (short)(a & 0xffffu);
    a = (unsigned)(u0 >> 32); hi[1] = (short)(a >> 16); lo[1] = (short)(a & 0xffffu);
    a = (unsigned)u1;         hi[2] = (short)(a >> 16); lo[2] = (short)(a & 0xffffu);
    a = (unsigned)(u1 >> 32); hi[3] = (short)(a >> 16); lo[3] = (short)(a & 0xffffu);
    a = (unsigned)u2;         hi[4] = (short)(a >> 16); lo[4] = (short)(a & 0xffffu);
    a = (unsigned)(u2 >> 32); hi[5] = (short)(a >> 16); lo[5] = (short)(a & 0xffffu);
    a = (unsigned)u3;         hi[6] = (short)(a >> 16); lo[6] = (short)(a & 0xffffu);
    a = (unsigned)(u3 >> 32); hi[7] = (short)(a >> 16); lo[7] = (short)(a & 0xffffu);
}

// ---------------- one-time converters ----------------

__global__ void convert_split(const float* __restrict__ src,
                              unsigned short* __restrict__ hi,
                              unsigned short* __restrict__ lo, int n4) {
    for (int i = blockIdx.x * blockDim.x + threadIdx.x; i < n4;
         i += gridDim.x * blockDim.x) {
        const float4 v = ((const float4*)src)[i];
        ushort4 h, l;
        float t;
        h.x = f2bf(v.x); t = v.x - bf2f(h.x); l.x = f2bf(t);
        h.y = f2bf(v.y); t = v.y - bf2f(h.y); l.y = f2bf(t);
        h.z = f2bf(v.z); t = v.z - bf2f(h.z); l.z = f2bf(t);
        h.w = f2bf(v.w); t = v.w - bf2f(h.w); l.w = f2bf(t);
        ((ushort4*)hi)[i] = h;
        ((ushort4*)lo)[i] = l;
    }
}

// Wpk[blk][half(hi=0,lo=1)][kstep 0..63][lane 0..63][8 elems].
// (blk, lane): m=lane&15, kg=(lane>>4)*8, row=(m>>2)*1024+blk*4+(m&3),
// k = kstep*32+kg; k<1024 -> W_ih, else W_hh.
__global__ void pack_W(const float* __restrict__ W_ih,
                       const float* __restrict__ W_hh,
                       unsigned short* __restrict__ Wpk) {
    const int i = blockIdx.x * blockDim.x + threadIdx.x;   // 0 .. 2,097,151
    const int lane = i & 63;
    const int s    = (i >> 6) & 63;
    const int half = (i >> 12) & 1;
    const int blk  = i >> 13;
    if (blk >= NBLK) return;
    const int m   = lane & 15;
    const int kg  = (lane >> 4) << 3;
    const int row = ((m >> 2) << 10) + (blk << 2) + (m & 3);
    const int k   = (s << 5) + kg;
    const float* src = (k < IN_DIM) ? (W_ih + (size_t)row * IN_DIM + k)
                                    : (W_hh + (size_t)row * HID + (k - IN_DIM));
    unsigned short v[8];
    #pragma unroll
    for (int e = 0; e < 8; ++e) {
        const float f = src[e];
        const unsigned short h = f2bf(f);
        v[e] = half ? f2bf(f - bf2f(h)) : h;
    }
    ushort4* dst = (ushort4*)(Wpk + (size_t)i * 8);
    dst[0] = make_ushort4(v[0], v[1], v[2], v[3]);
    dst[1] = make_ushort4(v[4], v[5], v[6], v[7]);
}

// h0 pack, bias combine, barrier region reset (4096 uints).
__global__ void prep_state(const float* __restrict__ h0,
                           const float* __restrict__ b_ih,
                           const float* __restrict__ b_hh,
                           unsigned* __restrict__ h_pk,
                           float* __restrict__ bias,
                           unsigned* __restrict__ bar) {
    const int i = blockIdx.x * blockDim.x + threadIdx.x;
    if (i < BH) {
        const float v = h0[i];
        const unsigned short hh = f2bf(v);
        const unsigned short hl = f2bf(v - bf2f(hh));
        h_pk[i] = ((unsigned)hh << 16) | (unsigned)hl;
    }
    if (i < 4 * HID) bias[i] = b_ih[i] + b_hh[i];
    if (i < 4096) bar[i] = 0u;
}

// ---------------- persistent LSTM scan ----------------
// Dynamic LDS: [0,128KiB) W fragments [2][64][64][8] bf16; [128KiB,144KiB)
// reduce buffer float[16][256].
// Barrier layout in bar[] (64-uint = 256B padded lines):
//   grp_cnt[g]   = bar[g*64]          g = blk & 15 (same-XCD groups of 16)
//   grp_phase[g] = bar[1024 + g*64]
//   root_cnt     = bar[2048]; root_phase = bar[2112]
__global__ __launch_bounds__(512, 2) void lstm_persistent(
    const unsigned short* __restrict__ x_hi,   // [T][32][1024]
    const unsigned short* __restrict__ x_lo,
    const unsigned short* __restrict__ Wpk,    // [256][2][64][64][8]
    unsigned* __restrict__ hA_pk,              // [32][1024] packed hi|lo
    unsigned* __restrict__ hB_pk,
    const float* __restrict__ bias,            // [4096]
    const float* __restrict__ c0,              // [32][1024]
    float* __restrict__ out,
    unsigned* __restrict__ bar)
{
    extern __shared__ unsigned char smem[];
    float* red = (float*)(smem + 131072);

    const int tid  = threadIdx.x;
    const int wave = tid >> 6;
    const int lane = tid & 63;
    const int blk  = blockIdx.x;

    // One-time: copy this block's 128 KiB W slice into LDS (coalesced).
    {
        const uint4* src = (const uint4*)Wpk + (size_t)blk * 8192;
        uint4* dst = (uint4*)smem;
        #pragma unroll
        for (int r = 0; r < 16; ++r) dst[r * 512 + tid] = src[r * 512 + tid];
    }

    const int m16    = lane & 15;
    const int kg     = (lane >> 4) << 3;
    const int off_b0 = m16 * HID + (wave << 7) + kg;   // batches 0-15 frag base
    const int off_b1 = off_b0 + 16 * HID;              // batches 16-31
    const int wbyte  = lane << 4;

    // Per-thread persistent epilogue state (tid < 128): c + bias.
    float c_reg = 0.f;
    float bias_reg[4] = {0.f, 0.f, 0.f, 0.f};
    const int b_own   = tid >> 2;
    const int jj      = tid & 3;
    const int col_own = (blk << 2) + jj;
    const int idx_own = b_own * HID + col_own;
    if (tid < 128) {
        #pragma unroll
        for (int g = 0; g < 4; ++g) bias_reg[g] = bias[g * HID + col_own];
        c_reg = c0[idx_own];
    }

    // Barrier pointers.
    unsigned* const gcnt = bar + ((blk & 15) * 64);
    unsigned* const gph  = bar + 1024 + ((blk & 15) * 64);
    unsigned* const rcnt = bar + 2048;
    unsigned* const rph  = bar + 2112;

    __syncthreads();

    unsigned* hin  = hA_pk;
    unsigned* hout = hB_pk;

    // Prefetch x fragments for the first step (plain cached loads).
    short8 pxh0[4], pxh1[4], pxl0[4], pxl1[4];
    {
        const unsigned short* xh = x_hi + (size_t)(T_STEPS - 1) * BH;
        const unsigned short* xl = x_lo + (size_t)(T_STEPS - 1) * BH;
        #pragma unroll
        for (int sq = 0; sq < 4; ++sq) {
            pxh0[sq] = *(const short8*)(xh + off_b0 + (sq << 5));
            pxh1[sq] = *(const short8*)(xh + off_b1 + (sq << 5));
            pxl0[sq] = *(const short8*)(xl + off_b0 + (sq << 5));
            pxl1[sq] = *(const short8*)(xl + off_b1 + (sq << 5));
        }
    }

    unsigned phase = 0;

    for (int i = 0; i < T_STEPS; ++i) {
        const int t = T_STEPS - 1 - i;

        f32x4 acc0 = {0.f, 0.f, 0.f, 0.f};
        f32x4 acc1 = {0.f, 0.f, 0.f, 0.f};

        // x-part MFMAs with prefetched fragments (covers h-load latency; the
        // compiler is free to hoist the independent h atomic-loads above).
        #pragma unroll
        for (int sq = 0; sq < 4; ++sq) {
            const int s = (wave << 2) + sq;
            const short8 whi = *(const short8*)(smem + (size_t)s * 1024 + wbyte);
            const short8 wlo = *(const short8*)(smem + (size_t)(64 + s) * 1024 + wbyte);
            acc0 = mfma16(whi, pxh0[sq], acc0);
            acc0 = mfma16(whi, pxl0[sq], acc0);
            acc0 = mfma16(wlo, pxh0[sq], acc0);
            acc1 = mfma16(whi, pxh1[sq], acc1);
            acc1 = mfma16(whi, pxl1[sq], acc1);
            acc1 = mfma16(wlo, pxh1[sq], acc1);
        }

        // h-part: coherence-point loads (always fresh; no fences needed),
        // unpack to hi/lo fragments, MFMA.
        #pragma unroll
        for (int sq = 0; sq < 4; ++sq) {
            const int s = 32 + (wave << 2) + sq;
            const short8 whi = *(const short8*)(smem + (size_t)s * 1024 + wbyte);
            const short8 wlo = *(const short8*)(smem + (size_t)(64 + s) * 1024 + wbyte);
            short8 hh0, hl0, hh1, hl1;
            unpack8((const unsigned long long*)(hin + off_b0 + (sq << 5)), hh0, hl0);
            unpack8((const unsigned long long*)(hin + off_b1 + (sq << 5)), hh1, hl1);
            acc0 = mfma16(whi, hh0, acc0);
            acc0 = mfma16(whi, hl0, acc0);
            acc0 = mfma16(wlo, hh0, acc0);
            acc1 = mfma16(whi, hh1, acc1);
            acc1 = mfma16(whi, hl1, acc1);
            acc1 = mfma16(wlo, hh1, acc1);
        }

        // Prefetch next step's x fragments (plain cached loads; L2 stays
        // warm now that nothing invalidates it).
        if (i + 1 < T_STEPS) {
            const unsigned short* xh = x_hi + (size_t)(t - 1) * BH;
            const unsigned short* xl = x_lo + (size_t)(t - 1) * BH;
            #pragma unroll
            for (int sq = 0; sq < 4; ++sq) {
                pxh0[sq] = *(const short8*)(xh + off_b0 + (sq << 5));
                pxh1[sq] = *(const short8*)(xh + off_b1 + (sq << 5));
                pxl0[sq] = *(const short8*)(xl + off_b0 + (sq << 5));
                pxl1[sq] = *(const short8*)(xl + off_b1 + (sq << 5));
            }
        }

        // Cross-wave reduce. C/D layout (m89): col=lane&15, row=4*(lane>>4)+r.
        {
            const int arow = (lane >> 4) << 2;
            const int acol = lane & 15;
            #pragma unroll
            for (int r = 0; r < 4; ++r) {
                red[((wave << 1) + 0) * 256 + (arow + r) * 16 + acol] = acc0[r];
                red[((wave << 1) + 1) * 256 + (arow + r) * 16 + acol] = acc1[r];
            }
        }
        __syncthreads();

        if (tid < 128) {
            const int mt  = b_own >> 4;
            const int c16 = b_own & 15;
            float val[4];
            #pragma unroll
            for (int g = 0; g < 4; ++g) {
                const int rr = ((g << 2) + jj) * 16 + c16;
                float sacc = 0.f;
                #pragma unroll
                for (int w = 0; w < 8; ++w) sacc += red[((w << 1) + mt) * 256 + rr];
                val[g] = sacc + bias_reg[g];
            }
            const float ig = 1.f / (1.f + __expf(-val[0]));
            const float fg = 1.f / (1.f + __expf(-val[1]));
            const float gg = tanhf(val[2]);
            const float og = 1.f / (1.f + __expf(-val[3]));
            c_reg = fg * c_reg + ig * gg;
            const float h_new = og * tanhf(c_reg);
            out[(size_t)t * BH + idx_own] = h_new;               // plain cached
            const unsigned short hh = f2bf(h_new);
            const unsigned short hl = f2bf(h_new - bf2f(hh));
            const unsigned pk = ((unsigned)hh << 16) | (unsigned)hl;
            __hip_atomic_store(hout + idx_own, pk, __ATOMIC_RELAXED,
                               __HIP_MEMORY_SCOPE_AGENT);        // to CP
            if (t == 0) out[(size_t)T_STEPS * BH + idx_own] = h_new;  // h_fin
        }

        // ---- tree grid barrier ----
        // __syncthreads drains each wave's vmcnt (incl. the h atomic stores)
        // before s_barrier => h globally visible before the arrival RMW.
        __syncthreads();
        if (tid == 0) {
            const unsigned target = phase + 1;
            const unsigned arrived = rmw_add(gcnt, 1u, __ATOMIC_RELAXED);
            if (arrived == 15u) {                 // group leader
                const unsigned r = rmw_add(rcnt, 1u, __ATOMIC_RELAXED);
                if (r == 15u) {                   // global last
                    rmw_add(rcnt, (unsigned)-16, __ATOMIC_RELAXED);
                    rmw_add(rph, 1u, __ATOMIC_RELEASE);   // orders reset first
                } else {
                    poll_ge<1>(rph, target);
                }
                rmw_add(gcnt, (unsigned)-16, __ATOMIC_RELAXED);
                rmw_add(gph, 1u, __ATOMIC_RELEASE);       // orders reset first
            } else {
                poll_ge<2>(gph, target);
            }
        }
        __syncthreads();
        phase += 1;

        // Swap h ping-pong.
        unsigned* th = hin; hin = hout; hout = th;
    }

    if (tid < 128)
        out[(size_t)T_STEPS * BH + BH + idx_own] = c_reg;   // c_fin
}

// ---------------- fallback (round-1, known-good, slow) ----------------
__global__ __launch_bounds__(256) void lstm_step_fused(
    const float* __restrict__ x_t, const float* __restrict__ h_prev,
    const float* __restrict__ c_prev, float* __restrict__ c_out,
    float* __restrict__ h_out, const float* __restrict__ W_ih,
    const float* __restrict__ W_hh, const float* __restrict__ b_ih,
    const float* __restrict__ b_hh) {
    __shared__ float xs[IN_DIM];
    __shared__ float hs[HID];
    const int tid = threadIdx.x;
    const int b   = blockIdx.x >> 2;
    const int j   = ((blockIdx.x & 3) << 8) | tid;
    ((float4*)xs)[tid] = ((const float4*)(x_t    + (size_t)b * IN_DIM))[tid];
    ((float4*)hs)[tid] = ((const float4*)(h_prev + (size_t)b * HID))[tid];
    __syncthreads();
    float a0 = b_ih[j] + b_hh[j];
    float a1 = b_ih[HID + j] + b_hh[HID + j];
    float a2 = b_ih[2*HID + j] + b_hh[2*HID + j];
    float a3 = b_ih[3*HID + j] + b_hh[3*HID + j];
    {
        const float4* wi0 = (const float4*)(W_ih + (size_t)(0*HID + j) * IN_DIM);
        const float4* wi1 = (const float4*)(W_ih + (size_t)(1*HID + j) * IN_DIM);
        const float4* wi2 = (const float4*)(W_ih + (size_t)(2*HID + j) * IN_DIM);
        const float4* wi3 = (const float4*)(W_ih + (size_t)(3*HID + j) * IN_DIM);
        const float4* xs4 = (const float4*)xs;
        #pragma unroll 4
        for (int k = 0; k < IN_DIM / 4; ++k) {
            const float4 xv = xs4[k]; float4 w;
            w = wi0[k]; a0 += xv.x*w.x + xv.y*w.y + xv.z*w.z + xv.w*w.w;
            w = wi1[k]; a1 += xv.x*w.x + xv.y*w.y + xv.z*w.z + xv.w*w.w;
            w = wi2[k]; a2 += xv.x*w.x + xv.y*w.y + xv.z*w.z + xv.w*w.w;
            w = wi3[k]; a3 += xv.x*w.x + xv.y*w.y + xv.z*w.z + xv.w*w.w;
        }
    }
    {
        const float4* wh0 = (const float4*)(W_hh + (size_t)(0*HID + j) * HID);
        const float4* wh1 = (const float4*)(W_hh + (size_t)(1*HID + j) * HID);
        const float4* wh2 = (const float4*)(W_hh + (size_t)(2*HID + j) * HID);
        const float4* wh3 = (const float4*)(W_hh + (size_t)(3*HID + j) * HID);
        const float4* hs4 = (const float4*)hs;
        #pragma unroll 4
        for (int k = 0; k < HID / 4; ++k) {
            const float4 hv = hs4[k]; float4 w;
            w = wh0[k]; a0 += hv.x*w.x + hv.y*w.y + hv.z*w.z + hv.w*w.w;
            w = wh1[k]; a1 += hv.x*w.x + hv.y*w.y + hv.z*w.z + hv.w*w.w;
            w = wh2[k]; a2 += hv.x*w.x + hv.y*w.y + hv.z*w.z + hv.w*w.w;
            w = wh3[k]; a3 += hv.x*w.x + hv.y*w.y + hv.z*w.z + hv.w*w.w;
        }
    }
    const float ig = 1.0f / (1.0f + __expf(-a0));
    const float fg = 1.0f / (1.0f + __expf(-a1));
    const float gg = tanhf(a2);
    const float og = 1.0f / (1.0f + __expf(-a3));
    const size_t idx = (size_t)b * HID + j;
    const float c_new = fg * c_prev[idx] + ig * gg;
    c_out[idx] = c_new;
    h_out[idx] = og * tanhf(c_new);
}

__global__ void lstm_finalize(const float* __restrict__ h_fin_src,
                              const float* __restrict__ c_fin_src,
                              float* __restrict__ dst_h,
                              float* __restrict__ dst_c) {
    const int i = blockIdx.x * blockDim.x + threadIdx.x;
    if (i < BH) { dst_h[i] = h_fin_src[i]; dst_c[i] = c_fin_src[i]; }
}

// ---------------- host ----------------

extern "C" void kernel_launch(void* const* d_in, const int* in_sizes, int n_in,
                              void* d_out, int out_size, void* d_ws, size_t ws_size,
                              hipStream_t stream) {
    const float* input = (const float*)d_in[0];
    const float* h0    = (const float*)d_in[1];
    const float* c0    = (const float*)d_in[2];
    const float* W_ih  = (const float*)d_in[3];
    const float* W_hh  = (const float*)d_in[4];
    const float* b_ih  = (const float*)d_in[5];
    const float* b_hh  = (const float*)d_in[6];
    float* out = (float*)d_out;

    // ws carve-up (bytes)
    const size_t OFF_XHI   = 0;                         // 64 MiB
    const size_t OFF_XLO   = OFF_XHI + 67108864ULL;     // 64 MiB
    const size_t OFF_WPK   = OFF_XLO + 67108864ULL;     // 32 MiB
    const size_t OFF_BIAS  = OFF_WPK + 33554432ULL;     // 16 KiB
    const size_t OFF_HA    = OFF_BIAS + 16384ULL;       // 128 KiB packed h A
    const size_t OFF_HB    = OFF_HA + 131072ULL;        // 128 KiB packed h B
    const size_t OFF_BAR   = OFF_HB + 131072ULL;        // 16 KiB barrier
    const size_t NEED      = OFF_BAR + 16384ULL;

    if (ws_size >= NEED) {
        unsigned char* w = (unsigned char*)d_ws;
        unsigned short* x_hi  = (unsigned short*)(w + OFF_XHI);
        unsigned short* x_lo  = (unsigned short*)(w + OFF_XLO);
        unsigned short* Wpk   = (unsigned short*)(w + OFF_WPK);
        float*          bias  = (float*)(w + OFF_BIAS);
        unsigned*       hA_pk = (unsigned*)(w + OFF_HA);
        unsigned*       hB_pk = (unsigned*)(w + OFF_HB);
        unsigned*       bar   = (unsigned*)(w + OFF_BAR);

        hipLaunchKernelGGL(convert_split, dim3(4096), dim3(256), 0, stream,
                           input, x_hi, x_lo, T_STEPS * BH / 4);
        hipLaunchKernelGGL(pack_W, dim3(8192), dim3(256), 0, stream,
                           W_ih, W_hh, Wpk);
        hipLaunchKernelGGL(prep_state, dim3(128), dim3(256), 0, stream,
                           h0, b_ih, b_hh, hA_pk, bias, bar);

        (void)hipFuncSetAttribute(reinterpret_cast<const void*>(lstm_persistent),
                                  hipFuncAttributeMaxDynamicSharedMemorySize, 147456);
        hipLaunchKernelGGL(lstm_persistent, dim3(NBLK), dim3(512), 147456, stream,
                           x_hi, x_lo, Wpk, hA_pk, hB_pk, bias, c0, out, bar);
    } else {
        // fallback: round-1 path (c scratch only)
        float* c_ws = (float*)d_ws;
        for (int t = T_STEPS - 1; t >= 0; --t) {
            const float* x_t = input + (size_t)t * BATCH * IN_DIM;
            const float* hp  = (t == T_STEPS - 1) ? h0 : out + (size_t)(t + 1) * BH;
            const float* cp  = (t == T_STEPS - 1) ? c0 : c_ws;
            hipLaunchKernelGGL(lstm_step_fused, dim3(128), dim3(256), 0, stream,
                               x_t, hp, cp, c_ws, out + (size_t)t * BH,
                               W_ih, W_hh, b_ih, b_hh);
        }
        hipLaunchKernelGGL(lstm_finalize, dim3(128), dim3(256), 0, stream,
                           out, c_ws,
                           out + (size_t)T_STEPS * BH,
                           out + (size_t)T_STEPS * BH + BH);
    }
}

// Round 7
// 12443.568 us; speedup vs baseline: 4.2243x; 1.1315x over previous
//
#include <hip/hip_runtime.h>

// ReverseLSTMLayer: T=1024, B=32, I=1024, H=1024, fp32 in/out.
// d_out layout: outputs [T*B*H] | h_fin [B*H] | c_fin [B*H].
//
// Round 7: persistent kernel (256 blocks x 512 threads, 1 block/CU via 144KB
// LDS). W hi/lo fragment-major LDS-resident; c in registers; x reg-prefetch.
// NEW vs round 6: h exchange is CACHED on the read side. Producers store
// packed h (bf16hi<<16|lo) with agent-scope atomic stores (write-through to
// the coherence point); consumers do ONE acquire-fence (buffer_inv) per
// block per step -- right after grid-barrier detection -- then read h with
// plain vectorized loads. Per-XCD L2 dedups the 256x read duplication
// (32 MB/step CP traffic -> ~1 MB/step). Barrier = round-6 tree (relaxed-RMW
// arrivals, RELEASE-RMW releases, relaxed-LOAD polling). Split-bf16 3-pass
// MFMA numerics (proven absmax 0.0039).

constexpr int T_STEPS = 1024;
constexpr int BATCH   = 32;
constexpr int IN_DIM  = 1024;
constexpr int HID     = 1024;
constexpr int BH      = BATCH * HID;   // 32768
constexpr int NBLK    = 256;

typedef __attribute__((ext_vector_type(8))) short  short8;
typedef __attribute__((ext_vector_type(4))) float  f32x4;

__device__ __forceinline__ unsigned short f2bf(float f) {
    union { float f; unsigned u; } x; x.f = f;
    unsigned r = (x.u + 0x7fffu + ((x.u >> 16) & 1u)) >> 16;
    return (unsigned short)r;
}
__device__ __forceinline__ float bf2f(unsigned short h) {
    union { unsigned u; float f; } x; x.u = ((unsigned)h) << 16;
    return x.f;
}
__device__ __forceinline__ f32x4 mfma16(short8 a, short8 b, f32x4 c) {
    return __builtin_amdgcn_mfma_f32_16x16x32_bf16(a, b, c, 0, 0, 0);
}

__device__ __forceinline__ unsigned rmw_add(unsigned* p, unsigned v, int order) {
    return __hip_atomic_fetch_add(p, v, order, __HIP_MEMORY_SCOPE_AGENT);
}
__device__ __forceinline__ unsigned flag_ld(const unsigned* p) {
    return __hip_atomic_load(p, __ATOMIC_RELAXED, __HIP_MEMORY_SCOPE_AGENT);
}
// Poll until *p >= target. Cheap relaxed loads; bounded-spin RMW fallback.
template <int SLP>
__device__ __forceinline__ void poll_ge(unsigned* p, unsigned target) {
    int spins = 0;
    while (flag_ld(p) < target) {
        __builtin_amdgcn_s_sleep(SLP);
        if (++spins > 16384) {
            if (rmw_add(p, 0u, __ATOMIC_RELAXED) >= target) break;
            spins = 8192;
        }
    }
}

// Unpack 8 packed-h uints (two uint4) into bf16-hi / bf16-lo fragments.
__device__ __forceinline__ void unpack4(uint4 a, uint4 b, short8& hi, short8& lo) {
    hi[0] = (short)(a.x >> 16); lo[0] = (short)(a.x & 0xffffu);
    hi[1] = (short)(a.y >> 16); lo[1] = (short)(a.y & 0xffffu);
    hi[2] = (short)(a.z >> 16); lo[2] = (short)(a.z & 0xffffu);
    hi[3] = (short)(a.w >> 16); lo[3] = (short)(a.w & 0xffffu);
    hi[4] = (short)(b.x >> 16); lo[4] = (short)(b.x & 0xffffu);
    hi[5] = (short)(b.y >> 16); lo[5] = (short)(b.y & 0xffffu);
    hi[6] = (short)(b.z >> 16); lo[6] = (short)(b.z & 0xffffu);
    hi[7] = (short)(b.w >> 16); lo[7] = (short)(b.w & 0xffffu);
}

// ---------------- one-time converters ----------------

__global__ void convert_split(const float* __restrict__ src,
                              unsigned short* __restrict__ hi,
                              unsigned short* __restrict__ lo, int n4) {
    for (int i = blockIdx.x * blockDim.x + threadIdx.x; i < n4;
         i += gridDim.x * blockDim.x) {
        const float4 v = ((const float4*)src)[i];
        ushort4 h, l;
        float t;
        h.x = f2bf(v.x); t = v.x - bf2f(h.x); l.x = f2bf(t);
        h.y = f2bf(v.y); t = v.y - bf2f(h.y); l.y = f2bf(t);
        h.z = f2bf(v.z); t = v.z - bf2f(h.z); l.z = f2bf(t);
        h.w = f2bf(v.w); t = v.w - bf2f(h.w); l.w = f2bf(t);
        ((ushort4*)hi)[i] = h;
        ((ushort4*)lo)[i] = l;
    }
}

// Wpk[blk][half(hi=0,lo=1)][kstep 0..63][lane 0..63][8 elems].
// (blk, lane): m=lane&15, kg=(lane>>4)*8, row=(m>>2)*1024+blk*4+(m&3),
// k = kstep*32+kg; k<1024 -> W_ih, else W_hh.
__global__ void pack_W(const float* __restrict__ W_ih,
                       const float* __restrict__ W_hh,
                       unsigned short* __restrict__ Wpk) {
    const int i = blockIdx.x * blockDim.x + threadIdx.x;   // 0 .. 2,097,151
    const int lane = i & 63;
    const int s    = (i >> 6) & 63;
    const int half = (i >> 12) & 1;
    const int blk  = i >> 13;
    if (blk >= NBLK) return;
    const int m   = lane & 15;
    const int kg  = (lane >> 4) << 3;
    const int row = ((m >> 2) << 10) + (blk << 2) + (m & 3);
    const int k   = (s << 5) + kg;
    const float* src = (k < IN_DIM) ? (W_ih + (size_t)row * IN_DIM + k)
                                    : (W_hh + (size_t)row * HID + (k - IN_DIM));
    unsigned short v[8];
    #pragma unroll
    for (int e = 0; e < 8; ++e) {
        const float f = src[e];
        const unsigned short h = f2bf(f);
        v[e] = half ? f2bf(f - bf2f(h)) : h;
    }
    ushort4* dst = (ushort4*)(Wpk + (size_t)i * 8);
    dst[0] = make_ushort4(v[0], v[1], v[2], v[3]);
    dst[1] = make_ushort4(v[4], v[5], v[6], v[7]);
}

// h0 pack, bias combine, barrier region reset (4096 uints).
__global__ void prep_state(const float* __restrict__ h0,
                           const float* __restrict__ b_ih,
                           const float* __restrict__ b_hh,
                           unsigned* __restrict__ h_pk,
                           float* __restrict__ bias,
                           unsigned* __restrict__ bar) {
    const int i = blockIdx.x * blockDim.x + threadIdx.x;
    if (i < BH) {
        const float v = h0[i];
        const unsigned short hh = f2bf(v);
        const unsigned short hl = f2bf(v - bf2f(hh));
        h_pk[i] = ((unsigned)hh << 16) | (unsigned)hl;
    }
    if (i < 4 * HID) bias[i] = b_ih[i] + b_hh[i];
    if (i < 4096) bar[i] = 0u;
}

// ---------------- persistent LSTM scan ----------------
// Dynamic LDS: [0,128KiB) W fragments [2][64][64][8] bf16; [128KiB,144KiB)
// reduce buffer float[16][256].
// Barrier layout in bar[] (64-uint = 256B padded lines):
//   grp_cnt[g]   = bar[g*64]          g = blk & 15 (same-XCD groups of 16)
//   grp_phase[g] = bar[1024 + g*64]
//   root_cnt     = bar[2048]; root_phase = bar[2112]
__global__ __launch_bounds__(512, 2) void lstm_persistent(
    const unsigned short* __restrict__ x_hi,   // [T][32][1024]
    const unsigned short* __restrict__ x_lo,
    const unsigned short* __restrict__ Wpk,    // [256][2][64][64][8]
    unsigned* __restrict__ hA_pk,              // [32][1024] packed hi|lo
    unsigned* __restrict__ hB_pk,
    const float* __restrict__ bias,            // [4096]
    const float* __restrict__ c0,              // [32][1024]
    float* __restrict__ out,
    unsigned* __restrict__ bar)
{
    extern __shared__ unsigned char smem[];
    float* red = (float*)(smem + 131072);

    const int tid  = threadIdx.x;
    const int wave = tid >> 6;
    const int lane = tid & 63;
    const int blk  = blockIdx.x;

    // One-time: copy this block's 128 KiB W slice into LDS (coalesced).
    {
        const uint4* src = (const uint4*)Wpk + (size_t)blk * 8192;
        uint4* dst = (uint4*)smem;
        #pragma unroll
        for (int r = 0; r < 16; ++r) dst[r * 512 + tid] = src[r * 512 + tid];
    }

    const int m16    = lane & 15;
    const int kg     = (lane >> 4) << 3;
    const int off_b0 = m16 * HID + (wave << 7) + kg;   // batches 0-15 frag base
    const int off_b1 = off_b0 + 16 * HID;              // batches 16-31
    const int wbyte  = lane << 4;

    // Per-thread persistent epilogue state (tid < 128): c + bias.
    float c_reg = 0.f;
    float bias_reg[4] = {0.f, 0.f, 0.f, 0.f};
    const int b_own   = tid >> 2;
    const int jj      = tid & 3;
    const int col_own = (blk << 2) + jj;
    const int idx_own = b_own * HID + col_own;
    if (tid < 128) {
        #pragma unroll
        for (int g = 0; g < 4; ++g) bias_reg[g] = bias[g * HID + col_own];
        c_reg = c0[idx_own];
    }

    // Barrier pointers.
    unsigned* const gcnt = bar + ((blk & 15) * 64);
    unsigned* const gph  = bar + 1024 + ((blk & 15) * 64);
    unsigned* const rcnt = bar + 2048;
    unsigned* const rph  = bar + 2112;

    __syncthreads();

    unsigned* hin  = hA_pk;
    unsigned* hout = hB_pk;

    // Prefetch x fragments for the first step (plain cached loads).
    short8 pxh0[4], pxh1[4], pxl0[4], pxl1[4];
    {
        const unsigned short* xh = x_hi + (size_t)(T_STEPS - 1) * BH;
        const unsigned short* xl = x_lo + (size_t)(T_STEPS - 1) * BH;
        #pragma unroll
        for (int sq = 0; sq < 4; ++sq) {
            pxh0[sq] = *(const short8*)(xh + off_b0 + (sq << 5));
            pxh1[sq] = *(const short8*)(xh + off_b1 + (sq << 5));
            pxl0[sq] = *(const short8*)(xl + off_b0 + (sq << 5));
            pxl1[sq] = *(const short8*)(xl + off_b1 + (sq << 5));
        }
    }

    unsigned phase = 0;

    for (int i = 0; i < T_STEPS; ++i) {
        const int t = T_STEPS - 1 - i;

        // Issue h loads EARLY (plain cached loads; post-fence so they miss
        // stale lines and fill from CP once per XCD, then L2-hit).
        uint4 hp0[8], hp1[8];
        #pragma unroll
        for (int sq = 0; sq < 4; ++sq) {
            const uint4* p0 = (const uint4*)(hin + off_b0 + (sq << 5));
            const uint4* p1 = (const uint4*)(hin + off_b1 + (sq << 5));
            hp0[sq * 2]     = p0[0];
            hp0[sq * 2 + 1] = p0[1];
            hp1[sq * 2]     = p1[0];
            hp1[sq * 2 + 1] = p1[1];
        }

        f32x4 acc0 = {0.f, 0.f, 0.f, 0.f};
        f32x4 acc1 = {0.f, 0.f, 0.f, 0.f};

        // x-part MFMAs with prefetched fragments (covers h-load latency).
        #pragma unroll
        for (int sq = 0; sq < 4; ++sq) {
            const int s = (wave << 2) + sq;
            const short8 whi = *(const short8*)(smem + (size_t)s * 1024 + wbyte);
            const short8 wlo = *(const short8*)(smem + (size_t)(64 + s) * 1024 + wbyte);
            acc0 = mfma16(whi, pxh0[sq], acc0);
            acc0 = mfma16(whi, pxl0[sq], acc0);
            acc0 = mfma16(wlo, pxh0[sq], acc0);
            acc1 = mfma16(whi, pxh1[sq], acc1);
            acc1 = mfma16(whi, pxl1[sq], acc1);
            acc1 = mfma16(wlo, pxh1[sq], acc1);
        }

        // h-part MFMAs from the early-loaded packed registers.
        #pragma unroll
        for (int sq = 0; sq < 4; ++sq) {
            const int s = 32 + (wave << 2) + sq;
            const short8 whi = *(const short8*)(smem + (size_t)s * 1024 + wbyte);
            const short8 wlo = *(const short8*)(smem + (size_t)(64 + s) * 1024 + wbyte);
            short8 hh0, hl0, hh1, hl1;
            unpack4(hp0[sq * 2], hp0[sq * 2 + 1], hh0, hl0);
            unpack4(hp1[sq * 2], hp1[sq * 2 + 1], hh1, hl1);
            acc0 = mfma16(whi, hh0, acc0);
            acc0 = mfma16(whi, hl0, acc0);
            acc0 = mfma16(wlo, hh0, acc0);
            acc1 = mfma16(whi, hh1, acc1);
            acc1 = mfma16(whi, hl1, acc1);
            acc1 = mfma16(wlo, hh1, acc1);
        }

        // Prefetch next step's x fragments.
        if (i + 1 < T_STEPS) {
            const unsigned short* xh = x_hi + (size_t)(t - 1) * BH;
            const unsigned short* xl = x_lo + (size_t)(t - 1) * BH;
            #pragma unroll
            for (int sq = 0; sq < 4; ++sq) {
                pxh0[sq] = *(const short8*)(xh + off_b0 + (sq << 5));
                pxh1[sq] = *(const short8*)(xh + off_b1 + (sq << 5));
                pxl0[sq] = *(const short8*)(xl + off_b0 + (sq << 5));
                pxl1[sq] = *(const short8*)(xl + off_b1 + (sq << 5));
            }
        }

        // Cross-wave reduce. C/D layout (m89): col=lane&15, row=4*(lane>>4)+r.
        {
            const int arow = (lane >> 4) << 2;
            const int acol = lane & 15;
            #pragma unroll
            for (int r = 0; r < 4; ++r) {
                red[((wave << 1) + 0) * 256 + (arow + r) * 16 + acol] = acc0[r];
                red[((wave << 1) + 1) * 256 + (arow + r) * 16 + acol] = acc1[r];
            }
        }
        __syncthreads();

        if (tid < 128) {
            const int mt  = b_own >> 4;
            const int c16 = b_own & 15;
            float val[4];
            #pragma unroll
            for (int g = 0; g < 4; ++g) {
                const int rr = ((g << 2) + jj) * 16 + c16;
                float sacc = 0.f;
                #pragma unroll
                for (int w = 0; w < 8; ++w) sacc += red[((w << 1) + mt) * 256 + rr];
                val[g] = sacc + bias_reg[g];
            }
            const float ig = 1.f / (1.f + __expf(-val[0]));
            const float fg = 1.f / (1.f + __expf(-val[1]));
            const float gg = tanhf(val[2]);
            const float og = 1.f / (1.f + __expf(-val[3]));
            c_reg = fg * c_reg + ig * gg;
            const float h_new = og * tanhf(c_reg);
            out[(size_t)t * BH + idx_own] = h_new;               // plain cached
            const unsigned short hh = f2bf(h_new);
            const unsigned short hl = f2bf(h_new - bf2f(hh));
            const unsigned pk = ((unsigned)hh << 16) | (unsigned)hl;
            __hip_atomic_store(hout + idx_own, pk, __ATOMIC_RELAXED,
                               __HIP_MEMORY_SCOPE_AGENT);        // to CP
            if (t == 0) out[(size_t)T_STEPS * BH + idx_own] = h_new;  // h_fin
        }

        // ---- tree grid barrier + one acquire-fence per block ----
        // __syncthreads drains each wave's vmcnt (incl. the h atomic stores)
        // before s_barrier => h globally visible before the arrival RMW.
        __syncthreads();
        if (tid == 0) {
            const unsigned target = phase + 1;
            const unsigned arrived = rmw_add(gcnt, 1u, __ATOMIC_RELAXED);
            if (arrived == 15u) {                 // group leader
                const unsigned r = rmw_add(rcnt, 1u, __ATOMIC_RELAXED);
                if (r == 15u) {                   // global last
                    rmw_add(rcnt, (unsigned)-16, __ATOMIC_RELAXED);
                    rmw_add(rph, 1u, __ATOMIC_RELEASE);   // orders reset first
                } else {
                    poll_ge<1>(rph, target);
                }
                rmw_add(gcnt, (unsigned)-16, __ATOMIC_RELAXED);
                rmw_add(gph, 1u, __ATOMIC_RELEASE);       // orders reset first
            } else {
                poll_ge<2>(gph, target);
            }
            // Acquire: invalidate stale L1/L2 h lines ONCE per block per
            // step. Next h reads miss -> fill fresh from CP -> L2 dedup.
            __builtin_amdgcn_fence(__ATOMIC_ACQUIRE, "agent");
        }
        __syncthreads();
        phase += 1;

        // Swap h ping-pong.
        unsigned* th = hin; hin = hout; hout = th;
    }

    if (tid < 128)
        out[(size_t)T_STEPS * BH + BH + idx_own] = c_reg;   // c_fin
}

// ---------------- fallback (round-1, known-good, slow) ----------------
__global__ __launch_bounds__(256) void lstm_step_fused(
    const float* __restrict__ x_t, const float* __restrict__ h_prev,
    const float* __restrict__ c_prev, float* __restrict__ c_out,
    float* __restrict__ h_out, const float* __restrict__ W_ih,
    const float* __restrict__ W_hh, const float* __restrict__ b_ih,
    const float* __restrict__ b_hh) {
    __shared__ float xs[IN_DIM];
    __shared__ float hs[HID];
    const int tid = threadIdx.x;
    const int b   = blockIdx.x >> 2;
    const int j   = ((blockIdx.x & 3) << 8) | tid;
    ((float4*)xs)[tid] = ((const float4*)(x_t    + (size_t)b * IN_DIM))[tid];
    ((float4*)hs)[tid] = ((const float4*)(h_prev + (size_t)b * HID))[tid];
    __syncthreads();
    float a0 = b_ih[j] + b_hh[j];
    float a1 = b_ih[HID + j] + b_hh[HID + j];
    float a2 = b_ih[2*HID + j] + b_hh[2*HID + j];
    float a3 = b_ih[3*HID + j] + b_hh[3*HID + j];
    {
        const float4* wi0 = (const float4*)(W_ih + (size_t)(0*HID + j) * IN_DIM);
        const float4* wi1 = (const float4*)(W_ih + (size_t)(1*HID + j) * IN_DIM);
        const float4* wi2 = (const float4*)(W_ih + (size_t)(2*HID + j) * IN_DIM);
        const float4* wi3 = (const float4*)(W_ih + (size_t)(3*HID + j) * IN_DIM);
        const float4* xs4 = (const float4*)xs;
        #pragma unroll 4
        for (int k = 0; k < IN_DIM / 4; ++k) {
            const float4 xv = xs4[k]; float4 w;
            w = wi0[k]; a0 += xv.x*w.x + xv.y*w.y + xv.z*w.z + xv.w*w.w;
            w = wi1[k]; a1 += xv.x*w.x + xv.y*w.y + xv.z*w.z + xv.w*w.w;
            w = wi2[k]; a2 += xv.x*w.x + xv.y*w.y + xv.z*w.z + xv.w*w.w;
            w = wi3[k]; a3 += xv.x*w.x + xv.y*w.y + xv.z*w.z + xv.w*w.w;
        }
    }
    {
        const float4* wh0 = (const float4*)(W_hh + (size_t)(0*HID + j) * HID);
        const float4* wh1 = (const float4*)(W_hh + (size_t)(1*HID + j) * HID);
        const float4* wh2 = (const float4*)(W_hh + (size_t)(2*HID + j) * HID);
        const float4* wh3 = (const float4*)(W_hh + (size_t)(3*HID + j) * HID);
        const float4* hs4 = (const float4*)hs;
        #pragma unroll 4
        for (int k = 0; k < HID / 4; ++k) {
            const float4 hv = hs4[k]; float4 w;
            w = wh0[k]; a0 += hv.x*w.x + hv.y*w.y + hv.z*w.z + hv.w*w.w;
            w = wh1[k]; a1 += hv.x*w.x + hv.y*w.y + hv.z*w.z + hv.w*w.w;
            w = wh2[k]; a2 += hv.x*w.x + hv.y*w.y + hv.z*w.z + hv.w*w.w;
            w = wh3[k]; a3 += hv.x*w.x + hv.y*w.y + hv.z*w.z + hv.w*w.w;
        }
    }
    const float ig = 1.0f / (1.0f + __expf(-a0));
    const float fg = 1.0f / (1.0f + __expf(-a1));
    const float gg = tanhf(a2);
    const float og = 1.0f / (1.0f + __expf(-a3));
    const size_t idx = (size_t)b * HID + j;
    const float c_new = fg * c_prev[idx] + ig * gg;
    c_out[idx] = c_new;
    h_out[idx] = og * tanhf(c_new);
}

__global__ void lstm_finalize(const float* __restrict__ h_fin_src,
                              const float* __restrict__ c_fin_src,
                              float* __restrict__ dst_h,
                              float* __restrict__ dst_c) {
    const int i = blockIdx.x * blockDim.x + threadIdx.x;
    if (i < BH) { dst_h[i] = h_fin_src[i]; dst_c[i] = c_fin_src[i]; }
}

// ---------------- host ----------------

extern "C" void kernel_launch(void* const* d_in, const int* in_sizes, int n_in,
                              void* d_out, int out_size, void* d_ws, size_t ws_size,
                              hipStream_t stream) {
    const float* input = (const float*)d_in[0];
    const float* h0    = (const float*)d_in[1];
    const float* c0    = (const float*)d_in[2];
    const float* W_ih  = (const float*)d_in[3];
    const float* W_hh  = (const float*)d_in[4];
    const float* b_ih  = (const float*)d_in[5];
    const float* b_hh  = (const float*)d_in[6];
    float* out = (float*)d_out;

    // ws carve-up (bytes)
    const size_t OFF_XHI   = 0;                         // 64 MiB
    const size_t OFF_XLO   = OFF_XHI + 67108864ULL;     // 64 MiB
    const size_t OFF_WPK   = OFF_XLO + 67108864ULL;     // 32 MiB
    const size_t OFF_BIAS  = OFF_WPK + 33554432ULL;     // 16 KiB
    const size_t OFF_HA    = OFF_BIAS + 16384ULL;       // 128 KiB packed h A
    const size_t OFF_HB    = OFF_HA + 131072ULL;        // 128 KiB packed h B
    const size_t OFF_BAR   = OFF_HB + 131072ULL;        // 16 KiB barrier
    const size_t NEED      = OFF_BAR + 16384ULL;

    if (ws_size >= NEED) {
        unsigned char* w = (unsigned char*)d_ws;
        unsigned short* x_hi  = (unsigned short*)(w + OFF_XHI);
        unsigned short* x_lo  = (unsigned short*)(w + OFF_XLO);
        unsigned short* Wpk   = (unsigned short*)(w + OFF_WPK);
        float*          bias  = (float*)(w + OFF_BIAS);
        unsigned*       hA_pk = (unsigned*)(w + OFF_HA);
        unsigned*       hB_pk = (unsigned*)(w + OFF_HB);
        unsigned*       bar   = (unsigned*)(w + OFF_BAR);

        hipLaunchKernelGGL(convert_split, dim3(4096), dim3(256), 0, stream,
                           input, x_hi, x_lo, T_STEPS * BH / 4);
        hipLaunchKernelGGL(pack_W, dim3(8192), dim3(256), 0, stream,
                           W_ih, W_hh, Wpk);
        hipLaunchKernelGGL(prep_state, dim3(128), dim3(256), 0, stream,
                           h0, b_ih, b_hh, hA_pk, bias, bar);

        (void)hipFuncSetAttribute(reinterpret_cast<const void*>(lstm_persistent),
                                  hipFuncAttributeMaxDynamicSharedMemorySize, 147456);
        hipLaunchKernelGGL(lstm_persistent, dim3(NBLK), dim3(512), 147456, stream,
                           x_hi, x_lo, Wpk, hA_pk, hB_pk, bias, c0, out, bar);
    } else {
        // fallback: round-1 path (c scratch only)
        float* c_ws = (float*)d_ws;
        for (int t = T_STEPS - 1; t >= 0; --t) {
            const float* x_t = input + (size_t)t * BATCH * IN_DIM;
            const float* hp  = (t == T_STEPS - 1) ? h0 : out + (size_t)(t + 1) * BH;
            const float* cp  = (t == T_STEPS - 1) ? c0 : c_ws;
            hipLaunchKernelGGL(lstm_step_fused, dim3(128), dim3(256), 0, stream,
                               x_t, hp, cp, c_ws, out + (size_t)t * BH,
                               W_ih, W_hh, b_ih, b_hh);
        }
        hipLaunchKernelGGL(lstm_finalize, dim3(128), dim3(256), 0, stream,
                           out, c_ws,
                           out + (size_t)T_STEPS * BH,
                           out + (size_t)T_STEPS * BH + BH);
    }
}